// Round 1
// baseline (236.066 us; speedup 1.0000x reference)
//
#include <hip/hip_runtime.h>

// LIF scan: mem_t = beta*mem + x_t - spk_{t-1}*thresh ; spk_t = (mem_t - thresh) > 0
// Shape [T=16, B=32, C=64, H=32, W=32]. Neurons independent -> 1 thread = 4 neurons (float4),
// carry mem/spk in registers across the T loop. Pure streaming, memory-bound (~268 MB).

constexpr int   T      = 16;
constexpr float BETA   = 0.9f;
constexpr float THRESH = 1.0f;

__global__ __launch_bounds__(256) void lif_kernel(const float* __restrict__ x,
                                                  float* __restrict__ out,
                                                  int n_per_t) {
    // Match numpy's separate-rounding fp32 exactly: no FMA contraction, else a
    // ~1-ulp difference flips spikes at the threshold boundary (error = 1.0).
#pragma clang fp contract(off)
    const int idx = (blockIdx.x * blockDim.x + threadIdx.x) * 4;
    if (idx >= n_per_t) return;

    float4 mem = make_float4(0.f, 0.f, 0.f, 0.f);
    float4 spk = make_float4(0.f, 0.f, 0.f, 0.f);

#pragma unroll
    for (int t = 0; t < T; ++t) {
        const size_t off = (size_t)t * (size_t)n_per_t + (size_t)idx;
        const float4 xt = *reinterpret_cast<const float4*>(x + off);

        mem.x = BETA * mem.x + xt.x - spk.x * THRESH;
        mem.y = BETA * mem.y + xt.y - spk.y * THRESH;
        mem.z = BETA * mem.z + xt.z - spk.z * THRESH;
        mem.w = BETA * mem.w + xt.w - spk.w * THRESH;

        spk.x = (mem.x - THRESH) > 0.f ? 1.f : 0.f;
        spk.y = (mem.y - THRESH) > 0.f ? 1.f : 0.f;
        spk.z = (mem.z - THRESH) > 0.f ? 1.f : 0.f;
        spk.w = (mem.w - THRESH) > 0.f ? 1.f : 0.f;

        *reinterpret_cast<float4*>(out + off) = spk;
    }
}

extern "C" void kernel_launch(void* const* d_in, const int* in_sizes, int n_in,
                              void* d_out, int out_size, void* d_ws, size_t ws_size,
                              hipStream_t stream) {
    const float* x   = (const float*)d_in[0];
    float*       out = (float*)d_out;

    const int total   = in_sizes[0];      // 33,554,432
    const int n_per_t = total / T;        // 2,097,152 (divisible by 4)
    const int threads = n_per_t / 4;      // 524,288

    dim3 block(256);
    dim3 grid((threads + block.x - 1) / block.x);  // 2048 blocks
    lif_kernel<<<grid, block, 0, stream>>>(x, out, n_per_t);
}

// Round 3
// 235.022 us; speedup vs baseline: 1.0044x; 1.0044x over previous
//
#include <hip/hip_runtime.h>

// LIF scan over T=16: mem_t = beta*mem + x_t - spk_{t-1}; spk_t = (mem_t - 1) > 0.
// Neurons independent -> 1 thread owns 4 neurons across all T.
// R3: same as R2 (prefetch all 16 loads for MLP, compute, burst 16 nontemporal
// stores) but with a clang ext_vector float4 — __builtin_nontemporal_store
// rejects HIP's float4 class type.

constexpr int   T      = 16;
constexpr float BETA   = 0.9f;
constexpr float THRESH = 1.0f;

typedef float f4 __attribute__((ext_vector_type(4)));

__global__ __launch_bounds__(256) void lif_kernel(const float* __restrict__ x,
                                                  float* __restrict__ out,
                                                  int n_per_t) {
    // No FMA contraction: must match numpy's two-rounding fp32 exactly, else
    // ~1-ulp drift flips spikes at the threshold (absmax = 1.0 cascades).
#pragma clang fp contract(off)
    const int idx = (blockIdx.x * blockDim.x + threadIdx.x) * 4;
    if (idx >= n_per_t) return;

    f4 v[T];  // holds x_t on the way in, spk_t on the way out

    // Phase 1: 16 independent loads in flight (coalesced per wave, 8 MB apart).
#pragma unroll
    for (int t = 0; t < T; ++t) {
        v[t] = *reinterpret_cast<const f4*>(x + (size_t)t * (size_t)n_per_t + (size_t)idx);
    }

    // Phase 2: the sequential recurrence, pure registers.
    f4 mem = (f4)(0.f);
    f4 spk = (f4)(0.f);
#pragma unroll
    for (int t = 0; t < T; ++t) {
#pragma unroll
        for (int j = 0; j < 4; ++j) {
            mem[j] = BETA * mem[j] + v[t][j] - spk[j] * THRESH;
            spk[j] = (mem[j] - THRESH) > 0.f ? 1.f : 0.f;
        }
        v[t] = spk;
    }

    // Phase 3: 16 stores, nontemporal (output never re-read on device).
#pragma unroll
    for (int t = 0; t < T; ++t) {
        __builtin_nontemporal_store(v[t],
            reinterpret_cast<f4*>(out + (size_t)t * (size_t)n_per_t + (size_t)idx));
    }
}

extern "C" void kernel_launch(void* const* d_in, const int* in_sizes, int n_in,
                              void* d_out, int out_size, void* d_ws, size_t ws_size,
                              hipStream_t stream) {
    const float* x   = (const float*)d_in[0];
    float*       out = (float*)d_out;

    const int total   = in_sizes[0];      // 33,554,432
    const int n_per_t = total / T;        // 2,097,152 (divisible by 4)
    const int threads = n_per_t / 4;      // 524,288

    dim3 block(256);
    dim3 grid((threads + block.x - 1) / block.x);  // 2048 blocks
    lif_kernel<<<grid, block, 0, stream>>>(x, out, n_per_t);
}